// Round 11
// baseline (375.449 us; speedup 1.0000x reference)
//
#include <hip/hip_runtime.h>

typedef unsigned short u16;
typedef unsigned int u32;
typedef short short8 __attribute__((ext_vector_type(8)));
typedef float f32x4 __attribute__((ext_vector_type(4)));

#define NB   512
#define NPG  211
#define NOBJ 10
#define NVAL 200
#define NE   420
#define NN   (NB * NPG)

__device__ __forceinline__ float bf2f(u16 u){
  union { unsigned i; float f; } v; v.i = ((unsigned)u) << 16; return v.f;
}
__device__ __forceinline__ u16 f2bf(float f){
  union { float f; unsigned i; } v; v.f = f;
  return (u16)((v.i + 0x7FFFu + ((v.i >> 16) & 1u)) >> 16);
}
__device__ __forceinline__ float lo_bf(u32 u){ union{u32 i;float f;}v; v.i=u<<16; return v.f; }
__device__ __forceinline__ float hi_bf(u32 u){ union{u32 i;float f;}v; v.i=u&0xffff0000u; return v.f; }
__device__ __forceinline__ u32 pack_bf(float a, float b){ return (u32)f2bf(a) | ((u32)f2bf(b)<<16); }
__device__ __forceinline__ float lrelu(float s){ return s > 0.f ? s : 0.2f * s; }
__device__ __forceinline__ short8 pack8(ushort4 a, ushort4 b){
  short8 v;
  v[0]=(short)a.x; v[1]=(short)a.y; v[2]=(short)a.z; v[3]=(short)a.w;
  v[4]=(short)b.x; v[5]=(short)b.y; v[6]=(short)b.z; v[7]=(short)b.w;
  return v;
}
// XOR swizzle inside a [*][128] u16 LDS tile, 4-element chunk granularity.
__device__ __forceinline__ int swz(int r, int c){
  return (r << 7) + (((c & ~3) ^ ((r & 15) << 2)) | (c & 3));
}
// 16B-chunk swizzled element index for the k_mm LDS tiles.
__device__ __forceinline__ int s16(int r, int c){
  return (r << 7) + ((((c >> 3) ^ (r & 15)) << 3) | (c & 7));
}

#define AS_GLOBAL(p) ((const __attribute__((address_space(1))) void*)((const void*)(p)))
#define AS_LDS(p)    ((__attribute__((address_space(3))) void*)((void*)(p)))

// ---------------- prep: transposed weights, f32 -> bf16 (ws) ----------------
__global__ __launch_bounds__(256) void k_prept(const float* __restrict__ W1, const float* __restrict__ W2,
                                               u16* __restrict__ W1t, u16* __restrict__ W2t){
  int gid = blockIdx.x * 256 + threadIdx.x;      // 320 blocks -> 81920
  if (gid < 16384){
    int k = gid >> 7, n = gid & 127;
    W1t[n * 128 + k] = f2bf(W1[k * 128 + n]);
  } else {
    int t = gid - 16384;
    int n = t >> 9, kk = t & 511;
    int h = kk >> 7, c = kk & 127;
    W2t[n * 512 + kk] = f2bf(W2[c * 512 + h * 128 + n]);
  }
}

// ---------------- prep: layer-2 attention vectors (ws, f32) ----------------
__global__ __launch_bounds__(256) void k_prepwm(const float* __restrict__ W2, const float* __restrict__ as2,
                                                const float* __restrict__ ad2,
                                                float* __restrict__ wms, float* __restrict__ wmd){
  int gid = blockIdx.x * 256 + threadIdx.x;      // 4 blocks -> 1024
  int which = gid >> 9, hk = gid & 511;
  int h = hk >> 7, k = hk & 127;
  const float* av = which ? ad2 : as2;
  float s = 0.f;
  for (int j = 0; j < 128; ++j)
    s += W2[k * 512 + h * 128 + j] * av[h * 128 + j];
  (which ? wmd : wms)[hk] = s;
}

// =====================================================================
// ===================== SPLIT PIPELINE KERNELS ========================
// =====================================================================

// ---- embed: x[n][c] bf16 (linear layout) ----
__global__ __launch_bounds__(256) void k_embed2(
    const float* __restrict__ head, const float* __restrict__ obj, const float* __restrict__ val,
    const float* __restrict__ Wh, const float* __restrict__ bh,
    const float* __restrict__ Wo, const float* __restrict__ bo,
    const float* __restrict__ Wv, const float* __restrict__ bv,
    u16* __restrict__ x){
  int gid = blockIdx.x * 256 + threadIdx.x;      // 13504 blocks = NN*32
  int n = gid >> 5, cc = (gid & 31) << 2;
  int g = n / NPG, loc = n - g * NPG;
  float a[4];
  if (loc == 0){
    const float* in = head + (size_t)g * 2;
    float i0 = in[0], i1 = in[1];
    #pragma unroll
    for (int t = 0; t < 4; ++t){ int c = cc + t; a[t] = bh[c] + i0 * Wh[c] + i1 * Wh[128 + c]; }
  } else if (loc <= NOBJ){
    const float* in = obj + ((size_t)g * NOBJ + (loc - 1)) * 2;
    float i0 = in[0], i1 = in[1];
    #pragma unroll
    for (int t = 0; t < 4; ++t){ int c = cc + t; a[t] = bo[c] + i0 * Wo[c] + i1 * Wo[128 + c]; }
  } else {
    const float* in = val + ((size_t)g * NVAL + (loc - 11)) * 5;
    float f[5];
    #pragma unroll
    for (int k = 0; k < 5; ++k) f[k] = in[k];
    #pragma unroll
    for (int t = 0; t < 4; ++t){
      int c = cc + t; float s = bv[c];
      #pragma unroll
      for (int k = 0; k < 5; ++k) s += f[k] * Wv[k * 128 + c];
      a[t] = s;
    }
  }
  ushort4 u;
  u.x = f2bf(fmaxf(a[0], 0.f)); u.y = f2bf(fmaxf(a[1], 0.f));
  u.z = f2bf(fmaxf(a[2], 0.f)); u.w = f2bf(fmaxf(a[3], 0.f));
  *(ushort4*)&x[(size_t)n * 128 + cc] = u;
}

// ---- CSR build: per-graph block ----
__global__ __launch_bounds__(256) void k_csr2(const int* __restrict__ eidx,
                                              int* __restrict__ coff, int* __restrict__ csrc){
  __shared__ int sEs[420], sEd[420], sTmp[256], sOff[212], sSrc[632];
  int g = blockIdx.x, tid = threadIdx.x;
  const int4* e4 = (const int4*)(eidx + (size_t)g * 840);
  for (int i = tid; i < 105; i += 256){ ((int4*)sEs)[i] = e4[i]; ((int4*)sEd)[i] = e4[105 + i]; }
  __syncthreads();
  int deg = 0;
  if (tid < NPG){
    deg = 1;
    const int4* p4 = (const int4*)sEd;
    #pragma unroll 4
    for (int i = 0; i < 105; ++i){
      int4 v = p4[i];
      deg += (v.x == tid) + (v.y == tid) + (v.z == tid) + (v.w == tid);
    }
  }
  int v = deg;
  #pragma unroll
  for (int st = 1; st < 256; st <<= 1){
    sTmp[tid] = v;
    __syncthreads();
    if (tid >= st) v += sTmp[tid - st];
    __syncthreads();
  }
  if (tid < NPG) sOff[tid] = v - deg;
  if (tid == NPG - 1) sOff[NPG] = v;
  __syncthreads();
  if (tid < NPG){
    int p = sOff[tid];
    sSrc[p++] = tid;                              // self loop first
    const int4* pd4 = (const int4*)sEd;
    const int4* ps4 = (const int4*)sEs;
    for (int i = 0; i < 105; ++i){
      int4 d = pd4[i]; int4 s = ps4[i];
      if (d.x == tid) sSrc[p++] = s.x;
      if (d.y == tid) sSrc[p++] = s.y;
      if (d.z == tid) sSrc[p++] = s.z;
      if (d.w == tid) sSrc[p++] = s.w;
    }
  }
  __syncthreads();
  if (tid < 212) coff[(size_t)g * 212 + tid] = sOff[tid];
  for (int i = tid; i < 631; i += 256) csrc[(size_t)g * 632 + i] = sSrc[i];
}

// ---- MFMA GEMM (R9-validated): C[Mx128] = sum_ch A_ch[Mx128] @ Bt^T ----
template<int KCH, bool RELU>
__global__ __launch_bounds__(512) void k_mm(const u16* __restrict__ A, size_t chunkStride,
                                            const u16* __restrict__ Bt, int bstride,
                                            const float* __restrict__ bias, u16* __restrict__ C){
  __shared__ u16 sA[128 * 128];
  __shared__ u16 sB[128 * 128];
  const int tid = threadIdx.x, lane = tid & 63, w = tid >> 6;
  const int l15 = lane & 15, lg = lane >> 4;
  const int row0 = blockIdx.x * 128;
  f32x4 acc[8];
  #pragma unroll
  for (int ni = 0; ni < 8; ++ni) acc[ni] = (f32x4){0,0,0,0};

  #pragma unroll 1
  for (int ch = 0; ch < KCH; ++ch){
    const u16* Ab = A + (size_t)ch * chunkStride + (size_t)row0 * 128;
    const u16* Bb = Bt + ch * 128;
    #pragma unroll
    for (int i = 0; i < 4; ++i){
      int r = w * 16 + i * 4 + (lane >> 4);
      int c16 = lane & 15;
      int sw = (c16 ^ (r & 15)) << 4;
      __builtin_amdgcn_global_load_lds(AS_GLOBAL((const char*)(Ab + (size_t)r * 128) + sw),
                                       AS_LDS(&sA[(w * 16 + i * 4) * 128]), 16, 0, 0);
      __builtin_amdgcn_global_load_lds(AS_GLOBAL((const char*)(Bb + (size_t)r * bstride) + sw),
                                       AS_LDS(&sB[(w * 16 + i * 4) * 128]), 16, 0, 0);
    }
    __syncthreads();
    #pragma unroll
    for (int kk = 0; kk < 4; ++kk){
      int k0 = kk * 32 + lg * 4;
      int rr = w * 16 + l15;
      short8 af = pack8(*(const ushort4*)&sA[s16(rr, k0)],
                        *(const ushort4*)&sA[s16(rr, k0 + 16)]);
      #pragma unroll
      for (int ni = 0; ni < 8; ++ni){
        int cc = ni * 16 + l15;
        short8 bf = pack8(*(const ushort4*)&sB[s16(cc, k0)],
                          *(const ushort4*)&sB[s16(cc, k0 + 16)]);
        acc[ni] = __builtin_amdgcn_mfma_f32_16x16x32_bf16(af, bf, acc[ni], 0, 0, 0);
      }
    }
    __syncthreads();
  }
  const int r0 = row0 + w * 16 + lg * 4;
  #pragma unroll
  for (int ni = 0; ni < 8; ++ni){
    int col = ni * 16 + l15;
    float bv = RELU ? bias[col] : 0.f;
    #pragma unroll
    for (int r = 0; r < 4; ++r){
      float v = acc[ni][r];
      if (RELU) v = fmaxf(v + bv, 0.f);
      C[(size_t)(r0 + r) * 128 + col] = f2bf(v);
    }
  }
}

// ---- att1 logits ----
__global__ __launch_bounds__(256) void k_att1k(const u16* __restrict__ xs1,
                                               const float* __restrict__ as1, const float* __restrict__ ad1,
                                               float* __restrict__ Ls, float* __restrict__ Ld){
  int t = blockIdx.x * 256 + threadIdx.x;        // 1688 blocks = NN*4
  int n = t >> 2, h = t & 3;
  const u16* xr = xs1 + (size_t)n * 128 + h * 32;
  float s = 0.f, d = 0.f;
  #pragma unroll
  for (int j = 0; j < 8; ++j){
    ushort4 xv = *(const ushort4*)(xr + j * 4);
    #pragma unroll
    for (int q = 0; q < 4; ++q){
      float xf = bf2f(((const u16*)&xv)[q]);
      int c = h * 32 + j * 4 + q;
      s += xf * as1[c];
      d += xf * ad1[c];
    }
  }
  Ls[t] = s; Ld[t] = d;
}

// ---- att2 logits ----
__global__ __launch_bounds__(256) void k_att2k(const u16* __restrict__ x1,
                                               const float* __restrict__ wms, const float* __restrict__ wmd,
                                               float* __restrict__ Ls, float* __restrict__ Ld){
  __shared__ float sw[1024];
  int tid = threadIdx.x;
  for (int i = tid; i < 512; i += 256) sw[i] = wms[i];
  for (int i = tid; i < 512; i += 256) sw[512 + i] = wmd[i];
  __syncthreads();
  int t = blockIdx.x * 256 + tid;                // 1688 blocks
  int n = t >> 2, h = t & 3;
  const u16* xr = x1 + (size_t)n * 128;
  const float* wsp = sw + h * 128;
  const float* wdp = sw + 512 + h * 128;
  float s = 0.f, d = 0.f;
  #pragma unroll
  for (int j = 0; j < 32; ++j){
    ushort4 xv = *(const ushort4*)(xr + j * 4);
    #pragma unroll
    for (int q = 0; q < 4; ++q){
      float xf = bf2f(((const u16*)&xv)[q]);
      s += xf * wsp[j * 4 + q];
      d += xf * wdp[j * 4 + q];
    }
  }
  Ls[t] = s; Ld[t] = d;
}

// ---- softmax weights ----
__global__ __launch_bounds__(256) void k_smk(const float* __restrict__ Ls, const float* __restrict__ Ld,
                                             const int* __restrict__ coff, const int* __restrict__ csrc,
                                             float* __restrict__ wn, float* __restrict__ rden, float fold){
  int g = blockIdx.x >> 2;
  int t = ((blockIdx.x & 3) << 8) + threadIdx.x; // 0..1023
  if (t >= NPG * 4) return;
  int dst = t >> 2, h = t & 3;
  int gb = g * NPG;
  int o0 = coff[(size_t)g * 212 + dst], o1 = coff[(size_t)g * 212 + dst + 1];
  const int* sp = csrc + (size_t)g * 632;
  float ad = Ld[(size_t)(gb + dst) * 4 + h];
  float m = -3e38f;
  for (int e = o0; e < o1; ++e) m = fmaxf(m, lrelu(Ls[(size_t)(gb + sp[e]) * 4 + h] + ad));
  float dn = 0.f;
  float* wp = wn + (size_t)g * 2528 + h * 632;
  for (int e = o0; e < o1; ++e){
    float ee = __expf(lrelu(Ls[(size_t)(gb + sp[e]) * 4 + h] + ad) - m);
    wp[e] = ee; dn += ee;
  }
  rden[(size_t)(gb + dst) * 4 + h] = fold / (dn + 1e-16f);
}

// ---- gat1: wave per dst, thread per col-pair; x1 = relu(b1 + A~xs1) ----
__global__ __launch_bounds__(256) void k_gat1k(const u16* __restrict__ xs1,
                                               const float* __restrict__ wn, const float* __restrict__ rden,
                                               const int* __restrict__ coff, const int* __restrict__ csrc,
                                               const float* __restrict__ b1, u16* __restrict__ x1){
  int bid = blockIdx.x;                          // 512*53
  int g = bid / 53, ch = bid - g * 53;
  int dst = ch * 4 + (threadIdx.x >> 6);
  if (dst >= NPG) return;
  int lane = threadIdx.x & 63;
  int cp = lane << 1, hh = lane >> 4;
  int gb = g * NPG;
  int o0 = coff[(size_t)g * 212 + dst], o1 = coff[(size_t)g * 212 + dst + 1];
  const int* sp = csrc + (size_t)g * 632;
  const float* wp = wn + (size_t)g * 2528 + hh * 632;
  float a0 = 0.f, a1 = 0.f;
  for (int e = o0; e < o1; ++e){
    int src = sp[e];
    u32 f = *(const u32*)&xs1[(size_t)(gb + src) * 128 + cp];
    float w = wp[e];
    a0 += w * lo_bf(f); a1 += w * hi_bf(f);
  }
  float rv = rden[(size_t)(gb + dst) * 4 + hh];
  *(u32*)&x1[(size_t)(gb + dst) * 128 + cp] =
    pack_bf(fmaxf(a0 * rv + b1[cp], 0.f), fmaxf(a1 * rv + b1[cp + 1], 0.f));
}

// ---- FUSED gat2 + gemm2 + final projections: one block per graph ----
// LDS: sX1 linear [211][128] (54016) | sY swz [211][128] (54016) |
//      sW f32[2528] (10112) | sDen f32[844] (3376) | sOff i32[212] (848) |
//      sSrc i32[632] (2528)  -> total 124896 B
__global__ __launch_bounds__(512) void k_gg2(
    const u16* __restrict__ x1, const float* __restrict__ wn, const float* __restrict__ rden,
    const int* __restrict__ coff, const int* __restrict__ csrc,
    const u16* __restrict__ W2t, const float* __restrict__ b2,
    const float* __restrict__ amask,
    const float* __restrict__ Wacc, const float* __restrict__ bacc,
    const float* __restrict__ Woff, const float* __restrict__ boff,
    const float* __restrict__ Wvf,  const float* __restrict__ bvf,
    float* __restrict__ out)
{
  __shared__ __align__(16) char sm[124896];
  u16*   sX1  = (u16*)sm;
  u16*   sY   = (u16*)(sm + 54016);
  float* sW   = (float*)(sm + 108032);
  float* sDen = (float*)(sm + 118144);
  int*   sOff = (int*)(sm + 121520);
  int*   sSrc = (int*)(sm + 122368);

  const int g = blockIdx.x, tid = threadIdx.x;
  const int lane = tid & 63, w = tid >> 6;
  const int l15 = lane & 15, lg = lane >> 4;
  const int cp = lane << 1;

  // ---- stage x1 tile (linear), wn, rden, csr (ALL full strided loops) ----
  {
    const uint4* src = (const uint4*)(x1 + (size_t)g * NPG * 128);
    uint4* dst = (uint4*)sX1;
    for (int i = tid; i < 3376; i += 512) dst[i] = src[i];
    const float* wsrc = wn + (size_t)g * 2528;
    for (int i = tid; i < 2528; i += 512) sW[i] = wsrc[i];
    const float* rsrc = rden + (size_t)g * 844;
    for (int i = tid; i < 844; i += 512) sDen[i] = rsrc[i];
    for (int i = tid; i < 212; i += 512) sOff[i] = coff[(size_t)g * 212 + i];
    const int* ssrc = csrc + (size_t)g * 632;
    for (int i = tid; i < 632; i += 512) sSrc[i] = ssrc[i];
  }
  __syncthreads();

  f32x4 acc[2][8];
  #pragma unroll
  for (int m = 0; m < 2; ++m)
    #pragma unroll
    for (int ni = 0; ni < 8; ++ni) acc[m][ni] = (f32x4){0,0,0,0};
  const int rt0 = w, rt1 = w + 8;
  const bool has1 = (rt1 < 14);

  #pragma unroll 1
  for (int h = 0; h < 4; ++h){
    // -- aggregate y_h into sY (swz), rden has 0.25/den folded --
    const float* wp = sW + h * 632;
    for (int dst = w; dst < NPG; dst += 8){
      int o0 = sOff[dst], o1 = sOff[dst + 1];
      float a0 = 0.f, a1 = 0.f;
      int e = o0;
      for (; e + 4 <= o1; e += 4){
        int s0 = sSrc[e], s1 = sSrc[e+1], s2 = sSrc[e+2], s3 = sSrc[e+3];
        u32 f0 = *(const u32*)&sX1[s0 * 128 + cp];
        u32 f1 = *(const u32*)&sX1[s1 * 128 + cp];
        u32 f2 = *(const u32*)&sX1[s2 * 128 + cp];
        u32 f3 = *(const u32*)&sX1[s3 * 128 + cp];
        float w0 = wp[e], w1 = wp[e+1], w2 = wp[e+2], w3 = wp[e+3];
        a0 += w0 * lo_bf(f0); a1 += w0 * hi_bf(f0);
        a0 += w1 * lo_bf(f1); a1 += w1 * hi_bf(f1);
        a0 += w2 * lo_bf(f2); a1 += w2 * hi_bf(f2);
        a0 += w3 * lo_bf(f3); a1 += w3 * hi_bf(f3);
      }
      for (; e < o1; ++e){
        int sn = sSrc[e];
        u32 f = *(const u32*)&sX1[sn * 128 + cp];
        float wv = wp[e];
        a0 += wv * lo_bf(f); a1 += wv * hi_bf(f);
      }
      float rv = sDen[dst * 4 + h];
      *(u32*)&sY[swz(dst, cp)] = pack_bf(a0 * rv, a1 * rv);
    }
    __syncthreads();
    // -- MFMA: acc += y_h @ W2_h^T (B-fragments batched from L2) --
    #pragma unroll
    for (int kk = 0; kk < 4; ++kk){
      int k0 = kk * 32 + lg * 4;
      short8 bf[8];
      #pragma unroll
      for (int ni = 0; ni < 8; ++ni){
        const u16* Bp = W2t + (size_t)(ni * 16 + l15) * 512 + h * 128 + k0;
        bf[ni] = pack8(*(const ushort4*)Bp, *(const ushort4*)(Bp + 16));
      }
      int rr0 = rt0 * 16 + l15; rr0 = rr0 < NPG ? rr0 : NPG - 1;
      short8 af0 = pack8(*(const ushort4*)&sY[swz(rr0, k0)],
                         *(const ushort4*)&sY[swz(rr0, k0 + 16)]);
      #pragma unroll
      for (int ni = 0; ni < 8; ++ni)
        acc[0][ni] = __builtin_amdgcn_mfma_f32_16x16x32_bf16(af0, bf[ni], acc[0][ni], 0, 0, 0);
      if (has1){
        int rr1 = rt1 * 16 + l15; rr1 = rr1 < NPG ? rr1 : NPG - 1;
        short8 af1 = pack8(*(const ushort4*)&sY[swz(rr1, k0)],
                           *(const ushort4*)&sY[swz(rr1, k0 + 16)]);
        #pragma unroll
        for (int ni = 0; ni < 8; ++ni)
          acc[1][ni] = __builtin_amdgcn_mfma_f32_16x16x32_bf16(af1, bf[ni], acc[1][ni], 0, 0, 0);
      }
    }
    __syncthreads();
  }

  // ---- out2 tile = relu(acc + b2) -> sX1 (linear; x1 no longer needed) ----
  #pragma unroll
  for (int m = 0; m < 2; ++m){
    if (m == 1 && !has1) break;
    int r0 = (m == 0 ? rt0 : rt1) * 16 + lg * 4;
    #pragma unroll
    for (int ni = 0; ni < 8; ++ni){
      int col = ni * 16 + l15;
      float bv = b2[col];
      #pragma unroll
      for (int r = 0; r < 4; ++r){
        int row = r0 + r;
        if (row < NPG) sX1[row * 128 + col] = f2bf(fmaxf(acc[m][ni][r] + bv, 0.f));
      }
    }
  }
  __syncthreads();

  // ---- final projections: 2 threads per output (203 outputs) ----
  if (tid < 406){
    int o = tid >> 1, q = tid & 1;
    const u16* row = sX1 + (size_t)((o < 200) ? (11 + o) : 0) * 128;
    float s = 0.f;
    if (o < 200){
      #pragma unroll
      for (int j = 0; j < 16; ++j){
        int c = q * 64 + j * 4;
        ushort4 xv = *(const ushort4*)(row + c);
        s += bf2f(xv.x)*Woff[c] + bf2f(xv.y)*Woff[c+1] + bf2f(xv.z)*Woff[c+2] + bf2f(xv.w)*Woff[c+3];
      }
    } else if (o < 202){
      int j2 = o - 200;
      #pragma unroll
      for (int j = 0; j < 16; ++j){
        int c = q * 64 + j * 4;
        ushort4 xv = *(const ushort4*)(row + c);
        s += bf2f(xv.x)*Wacc[c*2+j2] + bf2f(xv.y)*Wacc[(c+1)*2+j2]
           + bf2f(xv.z)*Wacc[(c+2)*2+j2] + bf2f(xv.w)*Wacc[(c+3)*2+j2];
      }
    } else {
      #pragma unroll
      for (int j = 0; j < 16; ++j){
        int c = q * 64 + j * 4;
        ushort4 xv = *(const ushort4*)(row + c);
        s += bf2f(xv.x)*Wvf[c] + bf2f(xv.y)*Wvf[c+1] + bf2f(xv.z)*Wvf[c+2] + bf2f(xv.w)*Wvf[c+3];
      }
    }
    s += __shfl_xor(s, 1);
    if (q == 0){
      if (o < 200){
        out[(size_t)g * 203 + 2 + o] = s + boff[0];
      } else if (o < 202){
        int j2 = o - 200;
        float lm = logf(amask[g * 2 + j2]);
        out[(size_t)g * 203 + j2] = s + bacc[j2] + fmaxf(lm, -3.402823466e38f);
      } else {
        out[(size_t)g * 203 + 202] = s + bvf[0];
      }
    }
  }
}

extern "C" void kernel_launch(void* const* d_in, const int* in_sizes, int n_in,
                              void* d_out, int out_size, void* d_ws, size_t ws_size,
                              hipStream_t stream){
  (void)in_sizes; (void)n_in; (void)out_size; (void)ws_size;
  const float* head = (const float*)d_in[0];
  const float* obj  = (const float*)d_in[1];
  const float* val  = (const float*)d_in[2];
  const int*   eidx = (const int*)d_in[3];
  const float* amask= (const float*)d_in[4];
  const float* Wh   = (const float*)d_in[5];
  const float* bh   = (const float*)d_in[6];
  const float* Wo   = (const float*)d_in[7];
  const float* bo   = (const float*)d_in[8];
  const float* Wv   = (const float*)d_in[9];
  const float* bv   = (const float*)d_in[10];
  const float* W1   = (const float*)d_in[11];
  const float* as1  = (const float*)d_in[12];
  const float* ad1  = (const float*)d_in[13];
  const float* b1   = (const float*)d_in[14];
  const float* W2   = (const float*)d_in[15];
  const float* as2  = (const float*)d_in[16];
  const float* ad2  = (const float*)d_in[17];
  const float* b2   = (const float*)d_in[18];
  const float* Wacc = (const float*)d_in[19];
  const float* bacc = (const float*)d_in[20];
  const float* Woff = (const float*)d_in[21];
  const float* boff = (const float*)d_in[22];
  const float* Wvf  = (const float*)d_in[23];
  const float* bvf  = (const float*)d_in[24];
  float* out = (float*)d_out;

  char* ws = (char*)d_ws;
  u16*   W1t = (u16*)ws;                     // @0,        32768
  u16*   W2t = (u16*)(ws + 32768);           // @32768,   131072
  float* wms = (float*)(ws + 163840);        // @163840,    2048
  float* wmd = (float*)(ws + 165888);        // @165888,    2048

  k_prept<<<320, 256, 0, stream>>>(W1, W2, W1t, W2t);
  k_prepwm<<<4, 256, 0, stream>>>(W2, as2, ad2, wms, wmd);

  int*   coff = (int*)(ws + 167936);       //   434176 -> ends   602112
  int*   csrc = (int*)(ws + 602112);       //  1294336 -> ends  1896448
  float* aLs  = (float*)(ws + 1896448);    //  1728512 -> ends  3624960
  float* aLd  = (float*)(ws + 3624960);    //  1728512 -> ends  5353472
  float* wn   = (float*)(ws + 5353472);    //  5177344 -> ends 10530816
  float* rden = (float*)(ws + 10530816);   //  1728512 -> ends 12259328
  u16*   x    = (u16*)(ws + 12259328);     // 27656192 -> ends 39915520  (x, then x1)
  u16*   xs1  = (u16*)(ws + 39915520);     // 27656192 -> ends 67571712  (xs1)

  k_embed2<<<NN * 32 / 256, 256, 0, stream>>>(head, obj, val, Wh, bh, Wo, bo, Wv, bv, x);
  k_csr2<<<NB, 256, 0, stream>>>(eidx, coff, csrc);
  k_mm<1, false><<<NN / 128, 512, 0, stream>>>(x, 0, W1t, 128, nullptr, xs1);
  k_att1k<<<NN * 4 / 256, 256, 0, stream>>>(xs1, as1, ad1, aLs, aLd);
  k_smk<<<NB * 4, 256, 0, stream>>>(aLs, aLd, coff, csrc, wn, rden, 1.0f);
  k_gat1k<<<NB * 53, 256, 0, stream>>>(xs1, wn, rden, coff, csrc, b1, x);   // x := x1
  k_att2k<<<NN * 4 / 256, 256, 0, stream>>>(x, wms, wmd, aLs, aLd);
  k_smk<<<NB * 4, 256, 0, stream>>>(aLs, aLd, coff, csrc, wn, rden, 0.25f);
  k_gg2<<<NB, 512, 0, stream>>>(x, wn, rden, coff, csrc, W2t, b2, amask,
                                Wacc, bacc, Woff, boff, Wvf, bvf, out);
}

// Round 12
// 262.210 us; speedup vs baseline: 1.4319x; 1.4319x over previous
//
#include <hip/hip_runtime.h>

typedef unsigned short u16;
typedef unsigned int u32;
typedef short short8 __attribute__((ext_vector_type(8)));
typedef float f32x4 __attribute__((ext_vector_type(4)));

#define NB   512
#define NPG  211
#define NOBJ 10
#define NVAL 200
#define NE   420
#define NN   (NB * NPG)

__device__ __forceinline__ float bf2f(u16 u){
  union { unsigned i; float f; } v; v.i = ((unsigned)u) << 16; return v.f;
}
__device__ __forceinline__ u16 f2bf(float f){
  union { float f; unsigned i; } v; v.f = f;
  return (u16)((v.i + 0x7FFFu + ((v.i >> 16) & 1u)) >> 16);
}
__device__ __forceinline__ float lo_bf(u32 u){ union{u32 i;float f;}v; v.i=u<<16; return v.f; }
__device__ __forceinline__ float hi_bf(u32 u){ union{u32 i;float f;}v; v.i=u&0xffff0000u; return v.f; }
__device__ __forceinline__ u32 pack_bf(float a, float b){ return (u32)f2bf(a) | ((u32)f2bf(b)<<16); }
__device__ __forceinline__ float lrelu(float s){ return s > 0.f ? s : 0.2f * s; }
__device__ __forceinline__ short8 pack8(ushort4 a, ushort4 b){
  short8 v;
  v[0]=(short)a.x; v[1]=(short)a.y; v[2]=(short)a.z; v[3]=(short)a.w;
  v[4]=(short)b.x; v[5]=(short)b.y; v[6]=(short)b.z; v[7]=(short)b.w;
  return v;
}
// 16B-chunk swizzled element index for the k_mm LDS tiles.
__device__ __forceinline__ int s16(int r, int c){
  return (r << 7) + ((((c >> 3) ^ (r & 15)) << 3) | (c & 7));
}

#define AS_GLOBAL(p) ((const __attribute__((address_space(1))) void*)((const void*)(p)))
#define AS_LDS(p)    ((__attribute__((address_space(3))) void*)((void*)(p)))

// ---------------- prep (fused): W1t, W2t transpose + wms/wmd vectors ----------------
__global__ __launch_bounds__(256) void k_prep(const float* __restrict__ W1, const float* __restrict__ W2,
                                              const float* __restrict__ as2, const float* __restrict__ ad2,
                                              u16* __restrict__ W1t, u16* __restrict__ W2t,
                                              float* __restrict__ wms, float* __restrict__ wmd){
  int gid = blockIdx.x * 256 + threadIdx.x;      // 324 blocks -> 82944
  if (gid < 16384){
    int k = gid >> 7, n = gid & 127;
    W1t[n * 128 + k] = f2bf(W1[k * 128 + n]);
  } else if (gid < 81920){
    int t = gid - 16384;
    int n = t >> 9, kk = t & 511;
    int h = kk >> 7, c = kk & 127;
    W2t[n * 512 + kk] = f2bf(W2[c * 512 + h * 128 + n]);
  } else {
    int t = gid - 81920;                          // 0..1023
    int which = t >> 9, hk = t & 511;
    int h = hk >> 7, k = hk & 127;
    const float* av = which ? ad2 : as2;
    float s = 0.f;
    for (int j = 0; j < 128; ++j)
      s += W2[k * 512 + h * 128 + j] * av[h * 128 + j];
    (which ? wmd : wms)[hk] = s;
  }
}

// ---- embed: x[n][c] bf16 (linear layout) ----
__global__ __launch_bounds__(256) void k_embed2(
    const float* __restrict__ head, const float* __restrict__ obj, const float* __restrict__ val,
    const float* __restrict__ Wh, const float* __restrict__ bh,
    const float* __restrict__ Wo, const float* __restrict__ bo,
    const float* __restrict__ Wv, const float* __restrict__ bv,
    u16* __restrict__ x){
  int gid = blockIdx.x * 256 + threadIdx.x;      // 13504 blocks = NN*32
  int n = gid >> 5, cc = (gid & 31) << 2;
  int g = n / NPG, loc = n - g * NPG;
  float a[4];
  if (loc == 0){
    const float* in = head + (size_t)g * 2;
    float i0 = in[0], i1 = in[1];
    #pragma unroll
    for (int t = 0; t < 4; ++t){ int c = cc + t; a[t] = bh[c] + i0 * Wh[c] + i1 * Wh[128 + c]; }
  } else if (loc <= NOBJ){
    const float* in = obj + ((size_t)g * NOBJ + (loc - 1)) * 2;
    float i0 = in[0], i1 = in[1];
    #pragma unroll
    for (int t = 0; t < 4; ++t){ int c = cc + t; a[t] = bo[c] + i0 * Wo[c] + i1 * Wo[128 + c]; }
  } else {
    const float* in = val + ((size_t)g * NVAL + (loc - 11)) * 5;
    float f[5];
    #pragma unroll
    for (int k = 0; k < 5; ++k) f[k] = in[k];
    #pragma unroll
    for (int t = 0; t < 4; ++t){
      int c = cc + t; float s = bv[c];
      #pragma unroll
      for (int k = 0; k < 5; ++k) s += f[k] * Wv[k * 128 + c];
      a[t] = s;
    }
  }
  ushort4 u;
  u.x = f2bf(fmaxf(a[0], 0.f)); u.y = f2bf(fmaxf(a[1], 0.f));
  u.z = f2bf(fmaxf(a[2], 0.f)); u.w = f2bf(fmaxf(a[3], 0.f));
  *(ushort4*)&x[(size_t)n * 128 + cc] = u;
}

// ---- CSR build: per-graph block ----
__global__ __launch_bounds__(256) void k_csr2(const int* __restrict__ eidx,
                                              int* __restrict__ coff, int* __restrict__ csrc){
  __shared__ int sEs[420], sEd[420], sTmp[256], sOff[212], sSrc[632];
  int g = blockIdx.x, tid = threadIdx.x;
  const int4* e4 = (const int4*)(eidx + (size_t)g * 840);
  for (int i = tid; i < 105; i += 256){ ((int4*)sEs)[i] = e4[i]; ((int4*)sEd)[i] = e4[105 + i]; }
  __syncthreads();
  int deg = 0;
  if (tid < NPG){
    deg = 1;
    const int4* p4 = (const int4*)sEd;
    #pragma unroll 4
    for (int i = 0; i < 105; ++i){
      int4 v = p4[i];
      deg += (v.x == tid) + (v.y == tid) + (v.z == tid) + (v.w == tid);
    }
  }
  int v = deg;
  #pragma unroll
  for (int st = 1; st < 256; st <<= 1){
    sTmp[tid] = v;
    __syncthreads();
    if (tid >= st) v += sTmp[tid - st];
    __syncthreads();
  }
  if (tid < NPG) sOff[tid] = v - deg;
  if (tid == NPG - 1) sOff[NPG] = v;
  __syncthreads();
  if (tid < NPG){
    int p = sOff[tid];
    sSrc[p++] = tid;                              // self loop first
    const int4* pd4 = (const int4*)sEd;
    const int4* ps4 = (const int4*)sEs;
    for (int i = 0; i < 105; ++i){
      int4 d = pd4[i]; int4 s = ps4[i];
      if (d.x == tid) sSrc[p++] = s.x;
      if (d.y == tid) sSrc[p++] = s.y;
      if (d.z == tid) sSrc[p++] = s.z;
      if (d.w == tid) sSrc[p++] = s.w;
    }
  }
  __syncthreads();
  if (tid < 212) coff[(size_t)g * 212 + tid] = sOff[tid];
  for (int i = tid; i < 631; i += 256) csrc[(size_t)g * 632 + i] = sSrc[i];
}

// ---- MFMA GEMM (R9-validated structure, generalized addressing) ----
// C[Mx128] = sum_ch A[:, ch-chunk] @ B[:, ch-chunk]^T
// A row r of chunk ch at: A + ch*chunkOff + r*aStride (u16 elems)
template<int KCH, bool RELU>
__global__ __launch_bounds__(512) void k_mm(const u16* __restrict__ A, int aStride, int chunkOff,
                                            const u16* __restrict__ Bt, int bstride,
                                            const float* __restrict__ bias, u16* __restrict__ C){
  __shared__ u16 sA[128 * 128];
  __shared__ u16 sB[128 * 128];
  const int tid = threadIdx.x, lane = tid & 63, w = tid >> 6;
  const int l15 = lane & 15, lg = lane >> 4;
  const int row0 = blockIdx.x * 128;
  f32x4 acc[8];
  #pragma unroll
  for (int ni = 0; ni < 8; ++ni) acc[ni] = (f32x4){0,0,0,0};

  #pragma unroll 1
  for (int ch = 0; ch < KCH; ++ch){
    const u16* Ab = A + (size_t)ch * chunkOff;
    const u16* Bb = Bt + ch * 128;
    #pragma unroll
    for (int i = 0; i < 4; ++i){
      int r = w * 16 + i * 4 + (lane >> 4);
      int c16 = lane & 15;
      int sw = (c16 ^ (r & 15)) << 4;
      __builtin_amdgcn_global_load_lds(AS_GLOBAL((const char*)(Ab + (size_t)(row0 + r) * aStride) + sw),
                                       AS_LDS(&sA[(w * 16 + i * 4) * 128]), 16, 0, 0);
      __builtin_amdgcn_global_load_lds(AS_GLOBAL((const char*)(Bb + (size_t)r * bstride) + sw),
                                       AS_LDS(&sB[(w * 16 + i * 4) * 128]), 16, 0, 0);
    }
    __syncthreads();
    #pragma unroll
    for (int kk = 0; kk < 4; ++kk){
      int k0 = kk * 32 + lg * 4;
      int rr = w * 16 + l15;
      short8 af = pack8(*(const ushort4*)&sA[s16(rr, k0)],
                        *(const ushort4*)&sA[s16(rr, k0 + 16)]);
      #pragma unroll
      for (int ni = 0; ni < 8; ++ni){
        int cc = ni * 16 + l15;
        short8 bf = pack8(*(const ushort4*)&sB[s16(cc, k0)],
                          *(const ushort4*)&sB[s16(cc, k0 + 16)]);
        acc[ni] = __builtin_amdgcn_mfma_f32_16x16x32_bf16(af, bf, acc[ni], 0, 0, 0);
      }
    }
    __syncthreads();
  }
  const int r0 = row0 + w * 16 + lg * 4;
  #pragma unroll
  for (int ni = 0; ni < 8; ++ni){
    int col = ni * 16 + l15;
    float bv = RELU ? bias[col] : 0.f;
    #pragma unroll
    for (int r = 0; r < 4; ++r){
      float v = acc[ni][r];
      if (RELU) v = fmaxf(v + bv, 0.f);
      C[(size_t)(r0 + r) * 128 + col] = f2bf(v);
    }
  }
}

// ---- FUSED att1 + softmax-weights: one block per graph ----
__global__ __launch_bounds__(512) void k_attsm1(const u16* __restrict__ xs1,
                                                const float* __restrict__ as1, const float* __restrict__ ad1,
                                                const int* __restrict__ coff, const int* __restrict__ csrc,
                                                float* __restrict__ wn, float* __restrict__ rden){
  __shared__ float sLs[844], sLd[844];
  const int g = blockIdx.x, tid = threadIdx.x;
  const int gb = g * NPG;
  // phase 1: logits (identical arithmetic to k_att1k)
  for (int t = tid; t < NPG * 4; t += 512){
    int n = t >> 2, h = t & 3;
    const u16* xr = xs1 + (size_t)(gb + n) * 128 + h * 32;
    float s = 0.f, d = 0.f;
    #pragma unroll
    for (int j = 0; j < 8; ++j){
      ushort4 xv = *(const ushort4*)(xr + j * 4);
      #pragma unroll
      for (int q = 0; q < 4; ++q){
        float xf = bf2f(((const u16*)&xv)[q]);
        int c = h * 32 + j * 4 + q;
        s += xf * as1[c];
        d += xf * ad1[c];
      }
    }
    sLs[t] = s; sLd[t] = d;
  }
  __syncthreads();
  // phase 2: per-(dst,h) softmax weights (identical arithmetic to k_smk, fold=1)
  for (int t = tid; t < NPG * 4; t += 512){
    int dst = t >> 2, h = t & 3;
    int o0 = coff[(size_t)g * 212 + dst], o1 = coff[(size_t)g * 212 + dst + 1];
    const int* sp = csrc + (size_t)g * 632;
    float ad = sLd[t];
    float m = -3e38f;
    for (int e = o0; e < o1; ++e) m = fmaxf(m, lrelu(sLs[sp[e] * 4 + h] + ad));
    float dn = 0.f;
    float* wp = wn + (size_t)g * 2528 + h * 632;
    for (int e = o0; e < o1; ++e){
      float ee = __expf(lrelu(sLs[sp[e] * 4 + h] + ad) - m);
      wp[e] = ee; dn += ee;
    }
    rden[(size_t)(gb + dst) * 4 + h] = 1.0f / (dn + 1e-16f);
  }
}

// ---- FUSED att2 + softmax-weights: one block per graph (fold=0.25) ----
__global__ __launch_bounds__(512) void k_attsm2(const u16* __restrict__ x1,
                                                const float* __restrict__ wms, const float* __restrict__ wmd,
                                                const int* __restrict__ coff, const int* __restrict__ csrc,
                                                float* __restrict__ wn, float* __restrict__ rden){
  __shared__ float sw[1024];
  __shared__ float sLs[844], sLd[844];
  const int g = blockIdx.x, tid = threadIdx.x;
  const int gb = g * NPG;
  for (int i = tid; i < 1024; i += 512) sw[i] = (i < 512) ? wms[i] : wmd[i - 512];
  __syncthreads();
  // phase 1: logits (identical arithmetic to k_att2k)
  for (int t = tid; t < NPG * 4; t += 512){
    int n = t >> 2, h = t & 3;
    const u16* xr = x1 + (size_t)(gb + n) * 128;
    const float* wsp = sw + h * 128;
    const float* wdp = sw + 512 + h * 128;
    float s = 0.f, d = 0.f;
    #pragma unroll
    for (int j = 0; j < 32; ++j){
      ushort4 xv = *(const ushort4*)(xr + j * 4);
      #pragma unroll
      for (int q = 0; q < 4; ++q){
        float xf = bf2f(((const u16*)&xv)[q]);
        s += xf * wsp[j * 4 + q];
        d += xf * wdp[j * 4 + q];
      }
    }
    sLs[t] = s; sLd[t] = d;
  }
  __syncthreads();
  // phase 2
  for (int t = tid; t < NPG * 4; t += 512){
    int dst = t >> 2, h = t & 3;
    int o0 = coff[(size_t)g * 212 + dst], o1 = coff[(size_t)g * 212 + dst + 1];
    const int* sp = csrc + (size_t)g * 632;
    float ad = sLd[t];
    float m = -3e38f;
    for (int e = o0; e < o1; ++e) m = fmaxf(m, lrelu(sLs[sp[e] * 4 + h] + ad));
    float dn = 0.f;
    float* wp = wn + (size_t)g * 2528 + h * 632;
    for (int e = o0; e < o1; ++e){
      float ee = __expf(lrelu(sLs[sp[e] * 4 + h] + ad) - m);
      wp[e] = ee; dn += ee;
    }
    rden[(size_t)(gb + dst) * 4 + h] = 0.25f / (dn + 1e-16f);
  }
}

// ---- gat1: wave per dst, thread per col-pair; x1 = relu(b1 + A~xs1) ----
__global__ __launch_bounds__(256) void k_gat1k(const u16* __restrict__ xs1,
                                               const float* __restrict__ wn, const float* __restrict__ rden,
                                               const int* __restrict__ coff, const int* __restrict__ csrc,
                                               const float* __restrict__ b1, u16* __restrict__ x1){
  int bid = blockIdx.x;                          // 512*53
  int g = bid / 53, ch = bid - g * 53;
  int dst = ch * 4 + (threadIdx.x >> 6);
  if (dst >= NPG) return;
  int lane = threadIdx.x & 63;
  int cp = lane << 1, hh = lane >> 4;
  int gb = g * NPG;
  int o0 = coff[(size_t)g * 212 + dst], o1 = coff[(size_t)g * 212 + dst + 1];
  const int* sp = csrc + (size_t)g * 632;
  const float* wp = wn + (size_t)g * 2528 + hh * 632;
  float a0 = 0.f, a1 = 0.f;
  for (int e = o0; e < o1; ++e){
    int src = sp[e];
    u32 f = *(const u32*)&xs1[(size_t)(gb + src) * 128 + cp];
    float w = wp[e];
    a0 += w * lo_bf(f); a1 += w * hi_bf(f);
  }
  float rv = rden[(size_t)(gb + dst) * 4 + hh];
  *(u32*)&x1[(size_t)(gb + dst) * 128 + cp] =
    pack_bf(fmaxf(a0 * rv + b1[cp], 0.f), fmaxf(a1 * rv + b1[cp + 1], 0.f));
}

// ---- gat2: wave per dst, all 4 heads; y n-major [n][512] (fold=0.25 in rden) ----
__global__ __launch_bounds__(256) void k_gat2k(const u16* __restrict__ x1,
                                               const float* __restrict__ wn, const float* __restrict__ rden,
                                               const int* __restrict__ coff, const int* __restrict__ csrc,
                                               u16* __restrict__ y){
  int bid = blockIdx.x;                          // 512*53
  int g = bid / 53, ch = bid - g * 53;
  int dst = ch * 4 + (threadIdx.x >> 6);
  if (dst >= NPG) return;
  int lane = threadIdx.x & 63;
  int cp = lane << 1;
  int gb = g * NPG;
  int o0 = coff[(size_t)g * 212 + dst], o1 = coff[(size_t)g * 212 + dst + 1];
  const int* sp = csrc + (size_t)g * 632;
  const float* wb = wn + (size_t)g * 2528;
  float a0[4] = {0,0,0,0}, a1[4] = {0,0,0,0};
  for (int e = o0; e < o1; ++e){
    int src = sp[e];
    u32 f = *(const u32*)&x1[(size_t)(gb + src) * 128 + cp];
    float xl = lo_bf(f), xh = hi_bf(f);
    #pragma unroll
    for (int h = 0; h < 4; ++h){
      float w = wb[h * 632 + e];
      a0[h] += w * xl; a1[h] += w * xh;
    }
  }
  u16* yr = y + (size_t)(gb + dst) * 512;
  #pragma unroll
  for (int h = 0; h < 4; ++h){
    float rv = rden[(size_t)(gb + dst) * 4 + h];
    *(u32*)&yr[h * 128 + cp] = pack_bf(a0[h] * rv, a1[h] * rv);
  }
}

// ---- final projections: 4 blocks/graph, 4 threads/output ----
__global__ __launch_bounds__(256) void k_final2(const u16* __restrict__ out2, const float* __restrict__ amask,
                                                const float* __restrict__ Wacc, const float* __restrict__ bacc,
                                                const float* __restrict__ Woff, const float* __restrict__ boff,
                                                const float* __restrict__ Wvf,  const float* __restrict__ bvf,
                                                float* __restrict__ out){
  int g = blockIdx.x >> 2;
  int t = ((blockIdx.x & 3) << 8) + threadIdx.x; // 0..1023
  if (t >= 812) return;
  int o = t >> 2, q = t & 3;
  float s = 0.f;
  if (o < 200){
    const u16* row = out2 + (size_t)(g * NPG + 11 + o) * 128;
    #pragma unroll
    for (int j = 0; j < 8; ++j){
      int c = q * 32 + j * 4;
      ushort4 xv = *(const ushort4*)(row + c);
      s += bf2f(xv.x)*Woff[c] + bf2f(xv.y)*Woff[c+1] + bf2f(xv.z)*Woff[c+2] + bf2f(xv.w)*Woff[c+3];
    }
  } else if (o < 202){
    int j2 = o - 200;
    const u16* row = out2 + (size_t)(g * NPG) * 128;
    #pragma unroll
    for (int j = 0; j < 8; ++j){
      int c = q * 32 + j * 4;
      ushort4 xv = *(const ushort4*)(row + c);
      s += bf2f(xv.x)*Wacc[c*2+j2] + bf2f(xv.y)*Wacc[(c+1)*2+j2]
         + bf2f(xv.z)*Wacc[(c+2)*2+j2] + bf2f(xv.w)*Wacc[(c+3)*2+j2];
    }
  } else {
    const u16* row = out2 + (size_t)(g * NPG) * 128;
    #pragma unroll
    for (int j = 0; j < 8; ++j){
      int c = q * 32 + j * 4;
      ushort4 xv = *(const ushort4*)(row + c);
      s += bf2f(xv.x)*Wvf[c] + bf2f(xv.y)*Wvf[c+1] + bf2f(xv.z)*Wvf[c+2] + bf2f(xv.w)*Wvf[c+3];
    }
  }
  s += __shfl_xor(s, 1);
  s += __shfl_xor(s, 2);
  if (q == 0){
    if (o < 200){
      out[(size_t)g * 203 + 2 + o] = s + boff[0];
    } else if (o < 202){
      int j2 = o - 200;
      float lm = logf(amask[g * 2 + j2]);
      out[(size_t)g * 203 + j2] = s + bacc[j2] + fmaxf(lm, -3.402823466e38f);
    } else {
      out[(size_t)g * 203 + 202] = s + bvf[0];
    }
  }
}

extern "C" void kernel_launch(void* const* d_in, const int* in_sizes, int n_in,
                              void* d_out, int out_size, void* d_ws, size_t ws_size,
                              hipStream_t stream){
  (void)in_sizes; (void)n_in; (void)out_size; (void)ws_size;
  const float* head = (const float*)d_in[0];
  const float* obj  = (const float*)d_in[1];
  const float* val  = (const float*)d_in[2];
  const int*   eidx = (const int*)d_in[3];
  const float* amask= (const float*)d_in[4];
  const float* Wh   = (const float*)d_in[5];
  const float* bh   = (const float*)d_in[6];
  const float* Wo   = (const float*)d_in[7];
  const float* bo   = (const float*)d_in[8];
  const float* Wv   = (const float*)d_in[9];
  const float* bv   = (const float*)d_in[10];
  const float* W1   = (const float*)d_in[11];
  const float* as1  = (const float*)d_in[12];
  const float* ad1  = (const float*)d_in[13];
  const float* b1   = (const float*)d_in[14];
  const float* W2   = (const float*)d_in[15];
  const float* as2  = (const float*)d_in[16];
  const float* ad2  = (const float*)d_in[17];
  const float* b2   = (const float*)d_in[18];
  const float* Wacc = (const float*)d_in[19];
  const float* bacc = (const float*)d_in[20];
  const float* Woff = (const float*)d_in[21];
  const float* boff = (const float*)d_in[22];
  const float* Wvf  = (const float*)d_in[23];
  const float* bvf  = (const float*)d_in[24];
  float* out = (float*)d_out;

  char* ws = (char*)d_ws;
  u16*   W1t = (u16*)ws;                     // @0,        32768
  u16*   W2t = (u16*)(ws + 32768);           // @32768,   131072
  float* wms = (float*)(ws + 163840);        // @163840,    2048
  float* wmd = (float*)(ws + 165888);        // @165888,    2048
  int*   coff = (int*)(ws + 167936);         //   434176 -> ends   602112
  int*   csrc = (int*)(ws + 602112);         //  1294336 -> ends  1896448
  float* wn   = (float*)(ws + 5353472);      //  5177344 -> ends 10530816
  float* rden = (float*)(ws + 10530816);     //  1728512 -> ends 12259328
  u16*   x    = (u16*)(ws + 12259328);       // 27656192 -> ends 39915520  (x, then x1)
  u16*   xs1  = (u16*)(ws + 39915520);       // 27656192 -> ends 67571712  (xs1, then out2)
  u16*   y    = (u16*)(ws + 67571712);       // 110624768 -> ends 178196480 (verified fits in R8)

  k_prep<<<324, 256, 0, stream>>>(W1, W2, as2, ad2, W1t, W2t, wms, wmd);
  k_embed2<<<NN * 32 / 256, 256, 0, stream>>>(head, obj, val, Wh, bh, Wo, bo, Wv, bv, x);
  k_csr2<<<NB, 256, 0, stream>>>(eidx, coff, csrc);
  k_mm<1, false><<<NN / 128, 512, 0, stream>>>(x, 128, 0, W1t, 128, nullptr, xs1);
  k_attsm1<<<NB, 512, 0, stream>>>(xs1, as1, ad1, coff, csrc, wn, rden);
  k_gat1k<<<NB * 53, 256, 0, stream>>>(xs1, wn, rden, coff, csrc, b1, x);   // x := x1
  k_attsm2<<<NB, 512, 0, stream>>>(x, wms, wmd, coff, csrc, wn, rden);
  k_gat2k<<<NB * 53, 256, 0, stream>>>(x, wn, rden, coff, csrc, y);         // y n-major [n][512]
  k_mm<4, true><<<NN / 128, 512, 0, stream>>>(y, 512, 128, W2t, 512, b2, xs1); // xs1 := out2
  k_final2<<<NB * 4, 256, 0, stream>>>(xs1, amask, Wacc, bacc, Woff, boff, Wvf, bvf, out);
}

// Round 13
// 253.812 us; speedup vs baseline: 1.4792x; 1.0331x over previous
//
#include <hip/hip_runtime.h>

typedef unsigned short u16;
typedef unsigned int u32;
typedef short short8 __attribute__((ext_vector_type(8)));
typedef float f32x4 __attribute__((ext_vector_type(4)));

#define NB   512
#define NPG  211
#define NOBJ 10
#define NVAL 200
#define NE   420
#define NN   (NB * NPG)

__device__ __forceinline__ float bf2f(u16 u){
  union { unsigned i; float f; } v; v.i = ((unsigned)u) << 16; return v.f;
}
__device__ __forceinline__ u16 f2bf(float f){
  union { float f; unsigned i; } v; v.f = f;
  return (u16)((v.i + 0x7FFFu + ((v.i >> 16) & 1u)) >> 16);
}
__device__ __forceinline__ float lo_bf(u32 u){ union{u32 i;float f;}v; v.i=u<<16; return v.f; }
__device__ __forceinline__ float hi_bf(u32 u){ union{u32 i;float f;}v; v.i=u&0xffff0000u; return v.f; }
__device__ __forceinline__ u32 pack_bf(float a, float b){ return (u32)f2bf(a) | ((u32)f2bf(b)<<16); }
__device__ __forceinline__ float lrelu(float s){ return s > 0.f ? s : 0.2f * s; }
__device__ __forceinline__ short8 pack8(ushort4 a, ushort4 b){
  short8 v;
  v[0]=(short)a.x; v[1]=(short)a.y; v[2]=(short)a.z; v[3]=(short)a.w;
  v[4]=(short)b.x; v[5]=(short)b.y; v[6]=(short)b.z; v[7]=(short)b.w;
  return v;
}
// 16B-chunk swizzled element index for the k_mm LDS tiles.
__device__ __forceinline__ int s16(int r, int c){
  return (r << 7) + ((((c >> 3) ^ (r & 15)) << 3) | (c & 7));
}

#define AS_GLOBAL(p) ((const __attribute__((address_space(1))) void*)((const void*)(p)))
#define AS_LDS(p)    ((__attribute__((address_space(3))) void*)((void*)(p)))

// ---------------- prep (fused): W1t, W2t transpose + wms/wmd + W2z ----------------
__global__ __launch_bounds__(256) void k_prep(const float* __restrict__ W1, const float* __restrict__ W2,
                                              const float* __restrict__ as2, const float* __restrict__ ad2,
                                              u16* __restrict__ W1t, u16* __restrict__ W2t,
                                              float* __restrict__ wms, float* __restrict__ wmd,
                                              u16* __restrict__ W2z){
  int gid = blockIdx.x * 256 + threadIdx.x;      // 580 blocks -> 148480
  if (gid < 16384){
    int k = gid >> 7, n = gid & 127;
    W1t[n * 128 + k] = f2bf(W1[k * 128 + n]);
  } else if (gid < 81920){
    int t = gid - 16384;
    int n = t >> 9, kk = t & 511;
    int h = kk >> 7, c = kk & 127;
    W2t[n * 512 + kk] = f2bf(W2[c * 512 + h * 128 + n]);
  } else if (gid < 82944){
    int t = gid - 81920;                          // 0..1023
    int which = t >> 9, hk = t & 511;
    int h = hk >> 7, k = hk & 127;
    const float* av = which ? ad2 : as2;
    float s = 0.f;
    for (int j = 0; j < 128; ++j)
      s += W2[k * 512 + h * 128 + j] * av[h * 128 + j];
    (which ? wmd : wms)[hk] = s;
  } else {
    int t = gid - 82944;                          // 0..65535
    int c = t >> 7, k = t & 127;                  // W2z[c][k] = W2[k][c]
    W2z[c * 128 + k] = f2bf(W2[k * 512 + c]);
  }
}

// ---- embed: x[n][c] bf16 (linear layout) ----
__global__ __launch_bounds__(256) void k_embed2(
    const float* __restrict__ head, const float* __restrict__ obj, const float* __restrict__ val,
    const float* __restrict__ Wh, const float* __restrict__ bh,
    const float* __restrict__ Wo, const float* __restrict__ bo,
    const float* __restrict__ Wv, const float* __restrict__ bv,
    u16* __restrict__ x){
  int gid = blockIdx.x * 256 + threadIdx.x;      // 13504 blocks = NN*32
  int n = gid >> 5, cc = (gid & 31) << 2;
  int g = n / NPG, loc = n - g * NPG;
  float a[4];
  if (loc == 0){
    const float* in = head + (size_t)g * 2;
    float i0 = in[0], i1 = in[1];
    #pragma unroll
    for (int t = 0; t < 4; ++t){ int c = cc + t; a[t] = bh[c] + i0 * Wh[c] + i1 * Wh[128 + c]; }
  } else if (loc <= NOBJ){
    const float* in = obj + ((size_t)g * NOBJ + (loc - 1)) * 2;
    float i0 = in[0], i1 = in[1];
    #pragma unroll
    for (int t = 0; t < 4; ++t){ int c = cc + t; a[t] = bo[c] + i0 * Wo[c] + i1 * Wo[128 + c]; }
  } else {
    const float* in = val + ((size_t)g * NVAL + (loc - 11)) * 5;
    float f[5];
    #pragma unroll
    for (int k = 0; k < 5; ++k) f[k] = in[k];
    #pragma unroll
    for (int t = 0; t < 4; ++t){
      int c = cc + t; float s = bv[c];
      #pragma unroll
      for (int k = 0; k < 5; ++k) s += f[k] * Wv[k * 128 + c];
      a[t] = s;
    }
  }
  ushort4 u;
  u.x = f2bf(fmaxf(a[0], 0.f)); u.y = f2bf(fmaxf(a[1], 0.f));
  u.z = f2bf(fmaxf(a[2], 0.f)); u.w = f2bf(fmaxf(a[3], 0.f));
  *(ushort4*)&x[(size_t)n * 128 + cc] = u;
}

// ---- CSR build: per-graph block ----
__global__ __launch_bounds__(256) void k_csr2(const int* __restrict__ eidx,
                                              int* __restrict__ coff, int* __restrict__ csrc){
  __shared__ int sEs[420], sEd[420], sTmp[256], sOff[212], sSrc[632];
  int g = blockIdx.x, tid = threadIdx.x;
  const int4* e4 = (const int4*)(eidx + (size_t)g * 840);
  for (int i = tid; i < 105; i += 256){ ((int4*)sEs)[i] = e4[i]; ((int4*)sEd)[i] = e4[105 + i]; }
  __syncthreads();
  int deg = 0;
  if (tid < NPG){
    deg = 1;
    const int4* p4 = (const int4*)sEd;
    #pragma unroll 4
    for (int i = 0; i < 105; ++i){
      int4 v = p4[i];
      deg += (v.x == tid) + (v.y == tid) + (v.z == tid) + (v.w == tid);
    }
  }
  int v = deg;
  #pragma unroll
  for (int st = 1; st < 256; st <<= 1){
    sTmp[tid] = v;
    __syncthreads();
    if (tid >= st) v += sTmp[tid - st];
    __syncthreads();
  }
  if (tid < NPG) sOff[tid] = v - deg;
  if (tid == NPG - 1) sOff[NPG] = v;
  __syncthreads();
  if (tid < NPG){
    int p = sOff[tid];
    sSrc[p++] = tid;                              // self loop first
    const int4* pd4 = (const int4*)sEd;
    const int4* ps4 = (const int4*)sEs;
    for (int i = 0; i < 105; ++i){
      int4 d = pd4[i]; int4 s = ps4[i];
      if (d.x == tid) sSrc[p++] = s.x;
      if (d.y == tid) sSrc[p++] = s.y;
      if (d.z == tid) sSrc[p++] = s.z;
      if (d.w == tid) sSrc[p++] = s.w;
    }
  }
  __syncthreads();
  if (tid < 212) coff[(size_t)g * 212 + tid] = sOff[tid];
  for (int i = tid; i < 631; i += 256) csrc[(size_t)g * 632 + i] = sSrc[i];
}

// ---- MFMA GEMM (R9-validated): C[Mx128] = sum_ch A @ Bt^T ----
template<int KCH, bool RELU>
__global__ __launch_bounds__(512) void k_mm(const u16* __restrict__ A, int aStride, int chunkOff,
                                            const u16* __restrict__ Bt, int bstride,
                                            const float* __restrict__ bias, u16* __restrict__ C){
  __shared__ u16 sA[128 * 128];
  __shared__ u16 sB[128 * 128];
  const int tid = threadIdx.x, lane = tid & 63, w = tid >> 6;
  const int l15 = lane & 15, lg = lane >> 4;
  const int row0 = blockIdx.x * 128;
  f32x4 acc[8];
  #pragma unroll
  for (int ni = 0; ni < 8; ++ni) acc[ni] = (f32x4){0,0,0,0};

  #pragma unroll 1
  for (int ch = 0; ch < KCH; ++ch){
    const u16* Ab = A + (size_t)ch * chunkOff;
    const u16* Bb = Bt + ch * 128;
    #pragma unroll
    for (int i = 0; i < 4; ++i){
      int r = w * 16 + i * 4 + (lane >> 4);
      int c16 = lane & 15;
      int sw = (c16 ^ (r & 15)) << 4;
      __builtin_amdgcn_global_load_lds(AS_GLOBAL((const char*)(Ab + (size_t)(row0 + r) * aStride) + sw),
                                       AS_LDS(&sA[(w * 16 + i * 4) * 128]), 16, 0, 0);
      __builtin_amdgcn_global_load_lds(AS_GLOBAL((const char*)(Bb + (size_t)r * bstride) + sw),
                                       AS_LDS(&sB[(w * 16 + i * 4) * 128]), 16, 0, 0);
    }
    __syncthreads();
    #pragma unroll
    for (int kk = 0; kk < 4; ++kk){
      int k0 = kk * 32 + lg * 4;
      int rr = w * 16 + l15;
      short8 af = pack8(*(const ushort4*)&sA[s16(rr, k0)],
                        *(const ushort4*)&sA[s16(rr, k0 + 16)]);
      #pragma unroll
      for (int ni = 0; ni < 8; ++ni){
        int cc = ni * 16 + l15;
        short8 bf = pack8(*(const ushort4*)&sB[s16(cc, k0)],
                          *(const ushort4*)&sB[s16(cc, k0 + 16)]);
        acc[ni] = __builtin_amdgcn_mfma_f32_16x16x32_bf16(af, bf, acc[ni], 0, 0, 0);
      }
    }
    __syncthreads();
  }
  const int r0 = row0 + w * 16 + lg * 4;
  #pragma unroll
  for (int ni = 0; ni < 8; ++ni){
    int col = ni * 16 + l15;
    float bv = RELU ? bias[col] : 0.f;
    #pragma unroll
    for (int r = 0; r < 4; ++r){
      float v = acc[ni][r];
      if (RELU) v = fmaxf(v + bv, 0.f);
      C[(size_t)(r0 + r) * 128 + col] = f2bf(v);
    }
  }
}

// ---- z-GEMM: z[n][0..512) = x1 @ W2 ; 4 col-chunks share each A tile ----
__global__ __launch_bounds__(512) void k_mmz(const u16* __restrict__ A,
                                             const u16* __restrict__ W2z,
                                             u16* __restrict__ z){
  __shared__ u16 sA[128 * 128];
  __shared__ u16 sB[128 * 128];
  const int tid = threadIdx.x, lane = tid & 63, w = tid >> 6;
  const int l15 = lane & 15, lg = lane >> 4;
  const int row0 = (blockIdx.x >> 2) * 128;
  const int cy   = blockIdx.x & 3;
  const u16* Bb = W2z + cy * 16384;              // [128 cols of this chunk][128]
  f32x4 acc[8];
  #pragma unroll
  for (int ni = 0; ni < 8; ++ni) acc[ni] = (f32x4){0,0,0,0};

  #pragma unroll
  for (int i = 0; i < 4; ++i){
    int r = w * 16 + i * 4 + (lane >> 4);
    int c16 = lane & 15;
    int sw = (c16 ^ (r & 15)) << 4;
    __builtin_amdgcn_global_load_lds(AS_GLOBAL((const char*)(A + (size_t)(row0 + r) * 128) + sw),
                                     AS_LDS(&sA[(w * 16 + i * 4) * 128]), 16, 0, 0);
    __builtin_amdgcn_global_load_lds(AS_GLOBAL((const char*)(Bb + (size_t)r * 128) + sw),
                                     AS_LDS(&sB[(w * 16 + i * 4) * 128]), 16, 0, 0);
  }
  __syncthreads();
  #pragma unroll
  for (int kk = 0; kk < 4; ++kk){
    int k0 = kk * 32 + lg * 4;
    int rr = w * 16 + l15;
    short8 af = pack8(*(const ushort4*)&sA[s16(rr, k0)],
                      *(const ushort4*)&sA[s16(rr, k0 + 16)]);
    #pragma unroll
    for (int ni = 0; ni < 8; ++ni){
      int cc = ni * 16 + l15;
      short8 bf = pack8(*(const ushort4*)&sB[s16(cc, k0)],
                        *(const ushort4*)&sB[s16(cc, k0 + 16)]);
      acc[ni] = __builtin_amdgcn_mfma_f32_16x16x32_bf16(af, bf, acc[ni], 0, 0, 0);
    }
  }
  const int r0 = row0 + w * 16 + lg * 4;
  #pragma unroll
  for (int ni = 0; ni < 8; ++ni){
    int col = cy * 128 + ni * 16 + l15;
    #pragma unroll
    for (int r = 0; r < 4; ++r)
      z[(size_t)(r0 + r) * 512 + col] = f2bf(acc[ni][r]);
  }
}

// ---- FUSED att1 + softmax-weights: one block per graph ----
__global__ __launch_bounds__(512) void k_attsm1(const u16* __restrict__ xs1,
                                                const float* __restrict__ as1, const float* __restrict__ ad1,
                                                const int* __restrict__ coff, const int* __restrict__ csrc,
                                                float* __restrict__ wn, float* __restrict__ rden){
  __shared__ float sLs[844], sLd[844];
  const int g = blockIdx.x, tid = threadIdx.x;
  const int gb = g * NPG;
  for (int t = tid; t < NPG * 4; t += 512){
    int n = t >> 2, h = t & 3;
    const u16* xr = xs1 + (size_t)(gb + n) * 128 + h * 32;
    float s = 0.f, d = 0.f;
    #pragma unroll
    for (int j = 0; j < 8; ++j){
      ushort4 xv = *(const ushort4*)(xr + j * 4);
      #pragma unroll
      for (int q = 0; q < 4; ++q){
        float xf = bf2f(((const u16*)&xv)[q]);
        int c = h * 32 + j * 4 + q;
        s += xf * as1[c];
        d += xf * ad1[c];
      }
    }
    sLs[t] = s; sLd[t] = d;
  }
  __syncthreads();
  for (int t = tid; t < NPG * 4; t += 512){
    int dst = t >> 2, h = t & 3;
    int o0 = coff[(size_t)g * 212 + dst], o1 = coff[(size_t)g * 212 + dst + 1];
    const int* sp = csrc + (size_t)g * 632;
    float ad = sLd[t];
    float m = -3e38f;
    for (int e = o0; e < o1; ++e) m = fmaxf(m, lrelu(sLs[sp[e] * 4 + h] + ad));
    float dn = 0.f;
    float* wp = wn + (size_t)g * 2528 + h * 632;
    for (int e = o0; e < o1; ++e){
      float ee = __expf(lrelu(sLs[sp[e] * 4 + h] + ad) - m);
      wp[e] = ee; dn += ee;
    }
    rden[(size_t)(gb + dst) * 4 + h] = 1.0f / (dn + 1e-16f);
  }
}

// ---- FUSED att2 + softmax-weights (fold=0.25) ----
__global__ __launch_bounds__(512) void k_attsm2(const u16* __restrict__ x1,
                                                const float* __restrict__ wms, const float* __restrict__ wmd,
                                                const int* __restrict__ coff, const int* __restrict__ csrc,
                                                float* __restrict__ wn, float* __restrict__ rden){
  __shared__ float sw[1024];
  __shared__ float sLs[844], sLd[844];
  const int g = blockIdx.x, tid = threadIdx.x;
  const int gb = g * NPG;
  for (int i = tid; i < 1024; i += 512) sw[i] = (i < 512) ? wms[i] : wmd[i - 512];
  __syncthreads();
  for (int t = tid; t < NPG * 4; t += 512){
    int n = t >> 2, h = t & 3;
    const u16* xr = x1 + (size_t)(gb + n) * 128;
    const float* wsp = sw + h * 128;
    const float* wdp = sw + 512 + h * 128;
    float s = 0.f, d = 0.f;
    #pragma unroll
    for (int j = 0; j < 32; ++j){
      ushort4 xv = *(const ushort4*)(xr + j * 4);
      #pragma unroll
      for (int q = 0; q < 4; ++q){
        float xf = bf2f(((const u16*)&xv)[q]);
        s += xf * wsp[j * 4 + q];
        d += xf * wdp[j * 4 + q];
      }
    }
    sLs[t] = s; sLd[t] = d;
  }
  __syncthreads();
  for (int t = tid; t < NPG * 4; t += 512){
    int dst = t >> 2, h = t & 3;
    int o0 = coff[(size_t)g * 212 + dst], o1 = coff[(size_t)g * 212 + dst + 1];
    const int* sp = csrc + (size_t)g * 632;
    float ad = sLd[t];
    float m = -3e38f;
    for (int e = o0; e < o1; ++e) m = fmaxf(m, lrelu(sLs[sp[e] * 4 + h] + ad));
    float dn = 0.f;
    float* wp = wn + (size_t)g * 2528 + h * 632;
    for (int e = o0; e < o1; ++e){
      float ee = __expf(lrelu(sLs[sp[e] * 4 + h] + ad) - m);
      wp[e] = ee; dn += ee;
    }
    rden[(size_t)(gb + dst) * 4 + h] = 0.25f / (dn + 1e-16f);
  }
}

// ---- gat1: wave per dst, thread per col-pair; x1 = relu(b1 + A~xs1) ----
__global__ __launch_bounds__(256) void k_gat1k(const u16* __restrict__ xs1,
                                               const float* __restrict__ wn, const float* __restrict__ rden,
                                               const int* __restrict__ coff, const int* __restrict__ csrc,
                                               const float* __restrict__ b1, u16* __restrict__ x1){
  int bid = blockIdx.x;                          // 512*53
  int g = bid / 53, ch = bid - g * 53;
  int dst = ch * 4 + (threadIdx.x >> 6);
  if (dst >= NPG) return;
  int lane = threadIdx.x & 63;
  int cp = lane << 1, hh = lane >> 4;
  int gb = g * NPG;
  int o0 = coff[(size_t)g * 212 + dst], o1 = coff[(size_t)g * 212 + dst + 1];
  const int* sp = csrc + (size_t)g * 632;
  const float* wp = wn + (size_t)g * 2528 + hh * 632;
  float a0 = 0.f, a1 = 0.f;
  for (int e = o0; e < o1; ++e){
    int src = sp[e];
    u32 f = *(const u32*)&xs1[(size_t)(gb + src) * 128 + cp];
    float w = wp[e];
    a0 += w * lo_bf(f); a1 += w * hi_bf(f);
  }
  float rv = rden[(size_t)(gb + dst) * 4 + hh];
  *(u32*)&x1[(size_t)(gb + dst) * 128 + cp] =
    pack_bf(fmaxf(a0 * rv + b1[cp], 0.f), fmaxf(a1 * rv + b1[cp + 1], 0.f));
}

// ---- FUSED gat2-aggregate (over z) + final projections ----
// out2[dst][c] = relu(b2[c] + sum_h rv_h * sum_e w[h][e] * z[src_e][h*128+c])
// then project to out. Only dsts {0, 11..210} are needed.
__global__ __launch_bounds__(256) void k_aggp(const u16* __restrict__ z,
                                              const float* __restrict__ wn, const float* __restrict__ rden,
                                              const int* __restrict__ coff, const int* __restrict__ csrc,
                                              const float* __restrict__ b2, const float* __restrict__ amask,
                                              const float* __restrict__ Wacc, const float* __restrict__ bacc,
                                              const float* __restrict__ Woff, const float* __restrict__ boff,
                                              const float* __restrict__ Wvf,  const float* __restrict__ bvf,
                                              float* __restrict__ out){
  int bid = blockIdx.x;                          // 512*51
  int g = bid / 51, chunk = bid - g * 51;
  int idx = chunk * 4 + (threadIdx.x >> 6);      // 0..203
  if (idx >= 201) return;
  int dst = (idx == 0) ? 0 : 10 + idx;           // {0, 11..210}
  int lane = threadIdx.x & 63;
  int cp = lane << 1;
  int gb = g * NPG;
  int o0 = coff[(size_t)g * 212 + dst], o1 = coff[(size_t)g * 212 + dst + 1];
  const int* sp = csrc + (size_t)g * 632;
  const float* wb = wn + (size_t)g * 2528;
  float a00 = 0, a01 = 0, a10 = 0, a11 = 0, a20 = 0, a21 = 0, a30 = 0, a31 = 0;
  for (int e = o0; e < o1; ++e){
    int src = sp[e];
    const u16* zr = z + (size_t)(gb + src) * 512 + cp;
    u32 f0 = *(const u32*)&zr[0];
    u32 f1 = *(const u32*)&zr[128];
    u32 f2 = *(const u32*)&zr[256];
    u32 f3 = *(const u32*)&zr[384];
    float w0 = wb[e], w1 = wb[632 + e], w2 = wb[1264 + e], w3 = wb[1896 + e];
    a00 += w0 * lo_bf(f0); a01 += w0 * hi_bf(f0);
    a10 += w1 * lo_bf(f1); a11 += w1 * hi_bf(f1);
    a20 += w2 * lo_bf(f2); a21 += w2 * hi_bf(f2);
    a30 += w3 * lo_bf(f3); a31 += w3 * hi_bf(f3);
  }
  float4 rv = *(const float4*)&rden[(size_t)(gb + dst) * 4];
  float o2a = fmaxf(b2[cp]     + rv.x * a00 + rv.y * a10 + rv.z * a20 + rv.w * a30, 0.f);
  float o2b = fmaxf(b2[cp + 1] + rv.x * a01 + rv.y * a11 + rv.z * a21 + rv.w * a31, 0.f);
  if (idx == 0){
    float pA0 = o2a * Wacc[cp * 2]     + o2b * Wacc[(cp + 1) * 2];
    float pA1 = o2a * Wacc[cp * 2 + 1] + o2b * Wacc[(cp + 1) * 2 + 1];
    float pV  = o2a * Wvf[cp]          + o2b * Wvf[cp + 1];
    #pragma unroll
    for (int s = 1; s < 64; s <<= 1){
      pA0 += __shfl_xor(pA0, s);
      pA1 += __shfl_xor(pA1, s);
      pV  += __shfl_xor(pV, s);
    }
    if (lane == 0){
      float lm0 = fmaxf(logf(amask[g * 2]),     -3.402823466e38f);
      float lm1 = fmaxf(logf(amask[g * 2 + 1]), -3.402823466e38f);
      out[(size_t)g * 203]       = pA0 + bacc[0] + lm0;
      out[(size_t)g * 203 + 1]   = pA1 + bacc[1] + lm1;
      out[(size_t)g * 203 + 202] = pV + bvf[0];
    }
  } else {
    float pO = o2a * Woff[cp] + o2b * Woff[cp + 1];
    #pragma unroll
    for (int s = 1; s < 64; s <<= 1) pO += __shfl_xor(pO, s);
    if (lane == 0) out[(size_t)g * 203 + 2 + (idx - 1)] = pO + boff[0];
  }
}

extern "C" void kernel_launch(void* const* d_in, const int* in_sizes, int n_in,
                              void* d_out, int out_size, void* d_ws, size_t ws_size,
                              hipStream_t stream){
  (void)in_sizes; (void)n_in; (void)out_size; (void)ws_size;
  const float* head = (const float*)d_in[0];
  const float* obj  = (const float*)d_in[1];
  const float* val  = (const float*)d_in[2];
  const int*   eidx = (const int*)d_in[3];
  const float* amask= (const float*)d_in[4];
  const float* Wh   = (const float*)d_in[5];
  const float* bh   = (const float*)d_in[6];
  const float* Wo   = (const float*)d_in[7];
  const float* bo   = (const float*)d_in[8];
  const float* Wv   = (const float*)d_in[9];
  const float* bv   = (const float*)d_in[10];
  const float* W1   = (const float*)d_in[11];
  const float* as1  = (const float*)d_in[12];
  const float* ad1  = (const float*)d_in[13];
  const float* b1   = (const float*)d_in[14];
  const float* W2   = (const float*)d_in[15];
  const float* as2  = (const float*)d_in[16];
  const float* ad2  = (const float*)d_in[17];
  const float* b2   = (const float*)d_in[18];
  const float* Wacc = (const float*)d_in[19];
  const float* bacc = (const float*)d_in[20];
  const float* Woff = (const float*)d_in[21];
  const float* boff = (const float*)d_in[22];
  const float* Wvf  = (const float*)d_in[23];
  const float* bvf  = (const float*)d_in[24];
  float* out = (float*)d_out;

  char* ws = (char*)d_ws;
  u16*   W1t = (u16*)ws;                     // @0,        32768
  u16*   W2t = (u16*)(ws + 32768);           // @32768,   131072 (kept: k_prep writes it)
  float* wms = (float*)(ws + 163840);        // @163840,    2048
  float* wmd = (float*)(ws + 165888);        // @165888,    2048
  int*   coff = (int*)(ws + 167936);         //   434176 -> ends   602112
  int*   csrc = (int*)(ws + 602112);         //  1294336 -> ends  1896448
  u16*   W2z  = (u16*)(ws + 1896448);        //   131072 -> ends  2027520
  float* wn   = (float*)(ws + 5353472);      //  5177344 -> ends 10530816
  float* rden = (float*)(ws + 10530816);     //  1728512 -> ends 12259328
  u16*   x    = (u16*)(ws + 12259328);       // 27656192 -> ends 39915520  (x, then x1)
  u16*   xs1  = (u16*)(ws + 39915520);       // 27656192 -> ends 67571712
  u16*   z    = (u16*)(ws + 67571712);       // 110624768 -> ends 178196480 (fits, verified R8)

  k_prep<<<580, 256, 0, stream>>>(W1, W2, as2, ad2, W1t, W2t, wms, wmd, W2z);
  k_embed2<<<NN * 32 / 256, 256, 0, stream>>>(head, obj, val, Wh, bh, Wo, bo, Wv, bv, x);
  k_csr2<<<NB, 256, 0, stream>>>(eidx, coff, csrc);
  k_mm<1, false><<<NN / 128, 512, 0, stream>>>(x, 128, 0, W1t, 128, nullptr, xs1);
  k_attsm1<<<NB, 512, 0, stream>>>(xs1, as1, ad1, coff, csrc, wn, rden);
  k_gat1k<<<NB * 53, 256, 0, stream>>>(xs1, wn, rden, coff, csrc, b1, x);   // x := x1
  k_attsm2<<<NB, 512, 0, stream>>>(x, wms, wmd, coff, csrc, wn, rden);
  k_mmz<<<(NN / 128) * 4, 512, 0, stream>>>(x, W2z, z);                     // z = x1 @ W2
  k_aggp<<<NB * 51, 256, 0, stream>>>(z, wn, rden, coff, csrc, b2, amask,
                                      Wacc, bacc, Woff, boff, Wvf, bvf, out);
}